// Round 4
// baseline (99.091 us; speedup 1.0000x reference)
//
#include <hip/hip_runtime.h>
#include <hip/hip_bf16.h>

// Problem constants
#define BDIM 8
#define CIN 32
#define COUT 32
#define WDIM 128
#define JDIM 16384           // 128*128
#define SDIM 1024
#define PARTS 32             // gather parts per batch (= COUT, so part == o)
#define SPP (SDIM / PARTS)   // 32 samples per part
#define TAG 0x5ca1ab1e       // != 0xAAAAAAAA poison, != 0

// ws layout:
//   bytes [0 .. 98304)        partials4[part][b][24] float4  (96 floats per (part,b))
//   bytes [98304 .. +16384)   flags[(part*BDIM+b)*16] int    (64B-spread flags)

// ---------------------------------------------------------------------------
// Single fused kernel. grid = 256 blocks (one per (b,o) output plane), 256 thr.
//  produce : block (b,o) gathers part o of batch b -> 96 partials (float4 stores)
//            -> __threadfence (agent release / L2 writeback) -> flag := TAG
//  sync    : t<32 spin on the 32 flags of batch b (all 256 blocks co-resident)
//  consume : __threadfence (agent acquire / cache inv), float4 loads of 32 parts,
//            contract with weight row o, stream the 64KB plane out
// ---------------------------------------------------------------------------
__global__ __launch_bounds__(256) void k_fused(const float* __restrict__ v,
                                               const float* __restrict__ w,
                                               const int* __restrict__ idx,
                                               float4* __restrict__ partials4,
                                               int* __restrict__ flags,
                                               float* __restrict__ out) {
    const int bo = blockIdx.x;         // 0..255
    const int b  = bo >> 5;
    const int o  = bo & 31;
    const int part = o;                // producer role: part == o
    const int t  = threadIdx.x;
    const int i  = t & 31;             // input channel
    const int sg = t >> 5;             // 0..7 sample subgroup

    __shared__ float red[8][96];
    __shared__ float pq[96];
    __shared__ float4 quar[4][24];
    __shared__ float coef[3];

    // ---------------- produce: gather SPP samples of (b, part) --------------
    {
        const float* vb = v + ((size_t)(b * CIN + i)) * JDIM;
        const float step = 2.0f / 127.0f;
        const int s0 = part * SPP + sg;
        const int j0 = idx[s0 +  0];
        const int j1 = idx[s0 +  8];
        const int j2 = idx[s0 + 16];
        const int j3 = idx[s0 + 24];
        const float v0 = vb[j0], v1 = vb[j1], v2 = vb[j2], v3 = vb[j3];

        const float x0 = -1.0f + (float)(j0 & (WDIM - 1)) * step;
        const float y0 = -1.0f + (float)(j0 >> 7) * step;
        const float x1 = -1.0f + (float)(j1 & (WDIM - 1)) * step;
        const float y1 = -1.0f + (float)(j1 >> 7) * step;
        const float x2 = -1.0f + (float)(j2 & (WDIM - 1)) * step;
        const float y2 = -1.0f + (float)(j2 >> 7) * step;
        const float x3 = -1.0f + (float)(j3 & (WDIM - 1)) * step;
        const float y3 = -1.0f + (float)(j3 >> 7) * step;

        red[sg][i * 3 + 0] = v0 + v1 + v2 + v3;
        red[sg][i * 3 + 1] = v0 * x0 + v1 * x1 + v2 * x2 + v3 * x3;
        red[sg][i * 3 + 2] = v0 * y0 + v1 * y1 + v2 * y2 + v3 * y3;
    }
    __syncthreads();

    if (t < 96) {
        float sum = 0.f;
#pragma unroll
        for (int g = 0; g < 8; ++g) sum += red[g][t];
        pq[t] = sum;
    }
    __syncthreads();

    if (t < 24) {   // normal vector stores; made visible by the release fence
        partials4[(part * BDIM + b) * 24 + t] = *reinterpret_cast<float4*>(&pq[t * 4]);
    }
    __syncthreads();
    if (t == 0) {
        __threadfence();   // agent release: partials reach device scope
        __hip_atomic_store(&flags[(part * BDIM + b) * 16], TAG,
                           __ATOMIC_RELEASE, __HIP_MEMORY_SCOPE_AGENT);
    }

    // ---------------- sync: wait for all 32 parts of batch b ----------------
    if (t < 32) {
        while (__hip_atomic_load(&flags[(t * BDIM + b) * 16],
                                 __ATOMIC_RELAXED, __HIP_MEMORY_SCOPE_AGENT) != TAG) {
            __builtin_amdgcn_s_sleep(2);
        }
    }
    __syncthreads();
    __threadfence();       // agent acquire: invalidate caches before normal loads

    // ---------------- consume: reduce 32 parts for batch b (float4) ---------
    if (t < 96) {
        const int s = t % 24;          // float4 slot
        const int q = t / 24;          // part quarter 0..3
        float4 acc = make_float4(0.f, 0.f, 0.f, 0.f);
#pragma unroll
        for (int p8 = 0; p8 < 8; ++p8) {
            const float4 x = partials4[((q * 8 + p8) * BDIM + b) * 24 + s];
            acc.x += x.x; acc.y += x.y; acc.z += x.z; acc.w += x.w;
        }
        quar[q][s] = acc;
    }
    __syncthreads();
    if (t < 24) {
        const float4 a0 = quar[0][t], a1 = quar[1][t], a2 = quar[2][t], a3 = quar[3][t];
        float4 tot;
        tot.x = a0.x + a1.x + a2.x + a3.x;
        tot.y = a0.y + a1.y + a2.y + a3.y;
        tot.z = a0.z + a1.z + a2.z + a3.z;
        tot.w = a0.w + a1.w + a2.w + a3.w;
        *reinterpret_cast<float4*>(&pq[t * 4]) = tot;
    }
    __syncthreads();

    // contract with weight row o (lanes 0..63; halves duplicate harmlessly)
    if (t < 64) {
        const int ci = t & 31;
        const float P  = pq[ci * 3 + 0];
        const float Q0 = pq[ci * 3 + 1];
        const float Q1 = pq[ci * 3 + 2];
        const float w0 = w[(o * CIN + ci) * 2 + 0];
        const float w1 = w[(o * CIN + ci) * 2 + 1];
        float t0 = P * w0;
        float t1 = P * w1;
        float kk = Q0 * w0 + Q1 * w1;
#pragma unroll
        for (int off = 16; off >= 1; off >>= 1) {
            t0 += __shfl_xor(t0, off);
            t1 += __shfl_xor(t1, off);
            kk += __shfl_xor(kk, off);
        }
        if (t == 0) {
            const float step = 2.0f / 127.0f;
            coef[0] = t0 * step;          // x slope
            coef[1] = t1 * step;          // y slope
            coef[2] = -(t0 + t1 + kk);    // constant (coords -1 offsets folded)
        }
    }
    __syncthreads();

    // ---------------- output: stream the 64KB plane --------------------------
    const float a  = coef[0];
    const float c  = coef[1];
    const float C0 = coef[2];
    float* outp = out + (size_t)bo * JDIM;

#pragma unroll
    for (int seg = 0; seg < 16; ++seg) {
        const int r = (seg * 256 + t) * 4;
        const int x = r & (WDIM - 1);     // r%4==0: float4 never splits a row
        const int y = r >> 7;
        const float base = (float)y * c + C0;
        float4 val;
        val.x = base + (float)(x + 0) * a;
        val.y = base + (float)(x + 1) * a;
        val.z = base + (float)(x + 2) * a;
        val.w = base + (float)(x + 3) * a;
        *reinterpret_cast<float4*>(outp + r) = val;
    }
}

// ---------------------------------------------------------------------------
extern "C" void kernel_launch(void* const* d_in, const int* in_sizes, int n_in,
                              void* d_out, int out_size, void* d_ws, size_t ws_size,
                              hipStream_t stream) {
    const float* v   = (const float*)d_in[0];
    const float* w   = (const float*)d_in[1];
    const int*   idx = (const int*)d_in[2];
    float* out = (float*)d_out;

    float4* partials4 = (float4*)d_ws;                    // 256*24 float4
    int*    flags     = (int*)((char*)d_ws + 98304);      // 256 flags, 64B-spread

    k_fused<<<256, 256, 0, stream>>>(v, w, idx, partials4, flags, out);
}

// Round 5
// 76.075 us; speedup vs baseline: 1.3025x; 1.3025x over previous
//
#include <hip/hip_runtime.h>
#include <hip/hip_bf16.h>

// Problem constants
#define BDIM 8
#define CIN 32
#define COUT 32
#define WDIM 128
#define JDIM 16384           // 128*128
#define SDIM 1024
#define PARTS 32             // S split across gather blocks
#define SPP (SDIM / PARTS)   // 32 samples per part

// ws layout (floats): partials[part][b][i*3 + {P,Q0,Q1}]  (32*8*96 floats)

// ---------------------------------------------------------------------------
// Kernel 1: gather-reduce over sampled pixels.
// grid = 256 blocks (b x part), 256 threads. 4 independent gathers/thread.
// HBM-bound: ~16 MB of random 64B lines (1024 pixels/plane ~= whole plane).
// ---------------------------------------------------------------------------
__global__ __launch_bounds__(256) void k_gather(const float* __restrict__ v,
                                                const int* __restrict__ idx,
                                                float* __restrict__ partials) {
    const int b    = blockIdx.x >> 5;        // 0..7
    const int part = blockIdx.x & (PARTS - 1);
    const int i    = threadIdx.x & 31;       // input channel
    const int sg   = threadIdx.x >> 5;       // 0..7

    const float* vb = v + ((size_t)(b * CIN + i)) * JDIM;
    const float step = 2.0f / 127.0f;

    const int s0 = part * SPP + sg;
    const int j0 = idx[s0 +  0];
    const int j1 = idx[s0 +  8];
    const int j2 = idx[s0 + 16];
    const int j3 = idx[s0 + 24];
    const float v0 = vb[j0], v1 = vb[j1], v2 = vb[j2], v3 = vb[j3];

    const float x0 = -1.0f + (float)(j0 & (WDIM - 1)) * step;
    const float y0 = -1.0f + (float)(j0 >> 7) * step;
    const float x1 = -1.0f + (float)(j1 & (WDIM - 1)) * step;
    const float y1 = -1.0f + (float)(j1 >> 7) * step;
    const float x2 = -1.0f + (float)(j2 & (WDIM - 1)) * step;
    const float y2 = -1.0f + (float)(j2 >> 7) * step;
    const float x3 = -1.0f + (float)(j3 & (WDIM - 1)) * step;
    const float y3 = -1.0f + (float)(j3 >> 7) * step;

    __shared__ float red[8][96];
    red[sg][i * 3 + 0] = v0 + v1 + v2 + v3;
    red[sg][i * 3 + 1] = v0 * x0 + v1 * x1 + v2 * x2 + v3 * x3;
    red[sg][i * 3 + 2] = v0 * y0 + v1 * y1 + v2 * y2 + v3 * y3;
    __syncthreads();

    if (threadIdx.x < 96) {
        float sum = 0.f;
#pragma unroll
        for (int g = 0; g < 8; ++g) sum += red[g][threadIdx.x];
        partials[((size_t)part * BDIM + b) * 96 + threadIdx.x] = sum;
    }
}

// ---------------------------------------------------------------------------
// Kernel 2: coefficient reduce + streaming output fill.
// grid = 256 blocks (one per (b,o) plane), 256 threads.
// Phase A: reduce 32 parts (L2-hot, 96 floats), dot with weight row o.
// Phase B: out[bo][r] = x*a + y*c + C0 -- 16x float4 stores per thread.
// ---------------------------------------------------------------------------
__global__ __launch_bounds__(256) void k_out(const float* __restrict__ partials,
                                             const float* __restrict__ w,
                                             float* __restrict__ out) {
    const int bo = blockIdx.x;         // 0..255 = b*32+o
    const int b  = bo >> 5;
    const int o  = bo & 31;
    const int t  = threadIdx.x;

    __shared__ float pq[96];
    __shared__ float coef[3];

    // Phase A1: sum partials over PARTS for this b (96 lanes, 32 loads each)
    if (t < 96) {
        float s = 0.f;
#pragma unroll
        for (int part = 0; part < PARTS; ++part)
            s += partials[((size_t)part * BDIM + b) * 96 + t];
        pq[t] = s;
    }
    __syncthreads();

    // Phase A2: 32-lane dot with weight row o, butterfly reduce
    if (t < 64) {
        const int ci = t & 31;
        const float P  = pq[ci * 3 + 0];
        const float Q0 = pq[ci * 3 + 1];
        const float Q1 = pq[ci * 3 + 2];
        const float w0 = w[(o * CIN + ci) * 2 + 0];
        const float w1 = w[(o * CIN + ci) * 2 + 1];
        float t0 = P * w0;
        float t1 = P * w1;
        float kk = Q0 * w0 + Q1 * w1;
#pragma unroll
        for (int off = 16; off >= 1; off >>= 1) {
            t0 += __shfl_xor(t0, off);
            t1 += __shfl_xor(t1, off);
            kk += __shfl_xor(kk, off);
        }
        if (t == 0) {
            const float step = 2.0f / 127.0f;
            coef[0] = t0 * step;          // x slope
            coef[1] = t1 * step;          // y slope
            coef[2] = -(t0 + t1 + kk);    // constant (coords -1 offsets folded)
        }
    }
    __syncthreads();

    // Phase B: stream the 64KB plane, fully coalesced float4
    const float a  = coef[0];
    const float c  = coef[1];
    const float C0 = coef[2];
    float* outp = out + (size_t)bo * JDIM;

#pragma unroll
    for (int seg = 0; seg < 16; ++seg) {
        const int r = (seg * 256 + t) * 4;
        const int x = r & (WDIM - 1);     // r%4==0: float4 never splits a row
        const int y = r >> 7;
        const float base = (float)y * c + C0;
        float4 val;
        val.x = base + (float)(x + 0) * a;
        val.y = base + (float)(x + 1) * a;
        val.z = base + (float)(x + 2) * a;
        val.w = base + (float)(x + 3) * a;
        *reinterpret_cast<float4*>(outp + r) = val;
    }
}

// ---------------------------------------------------------------------------
extern "C" void kernel_launch(void* const* d_in, const int* in_sizes, int n_in,
                              void* d_out, int out_size, void* d_ws, size_t ws_size,
                              hipStream_t stream) {
    const float* v   = (const float*)d_in[0];
    const float* w   = (const float*)d_in[1];
    const int*   idx = (const int*)d_in[2];
    float* out = (float*)d_out;

    float* partials = (float*)d_ws;    // 32*8*96 floats

    k_gather<<<BDIM * PARTS, 256, 0, stream>>>(v, idx, partials);
    k_out<<<256, 256, 0, stream>>>(partials, w, out);
}